// Round 1
// baseline (7466.022 us; speedup 1.0000x reference)
//
#include <hip/hip_runtime.h>

#define HID 51
#define G4  204      // 4*HID
#define TSEQ 512
#define FUT 16
#define OT  (TSEQ + FUT)
#define KP  52       // padded dot length (13 * float4)

__device__ __forceinline__ float sigf(float x) {
    return 1.0f / (1.0f + __expf(-x));
}
__device__ __forceinline__ float tanhf_(float x) {
    // tanh(x) = 1 - 2/(1+exp(2x)); saturates correctly at +/-inf
    return 1.0f - 2.0f / (1.0f + __expf(2.0f * x));
}

__global__ __launch_bounds__(256, 2) void lstm_seq_kernel(
    const float* __restrict__ input,   // [B, TSEQ]
    const float* __restrict__ W_ih1,   // [204, 1]
    const float* __restrict__ W_hh1,   // [204, 51]
    const float* __restrict__ b_ih1,   // [204]
    const float* __restrict__ b_hh1,   // [204]
    const float* __restrict__ W_ih2,   // [204, 51]
    const float* __restrict__ W_hh2,   // [204, 51]
    const float* __restrict__ b_ih2,   // [204]
    const float* __restrict__ b_hh2,   // [204]
    const float* __restrict__ W_lin,   // [1, 51]
    const float* __restrict__ b_lin,   // [1]
    float* __restrict__ out)           // [B, OT]
{
    const int b = blockIdx.x;
    const int j = threadIdx.x;

    __shared__ __align__(16) float h1s[KP];
    __shared__ __align__(16) float h2s[KP];
    __shared__ float gs[G4];
    __shared__ float xs;

    // ---- one-time init ----
    if (j < KP) { h1s[j] = 0.0f; h2s[j] = 0.0f; }

    const int jc = (j < G4) ? j : (G4 - 1);   // clamp padding threads (no OOB)

    // per-thread weight registers (statically indexed via full unroll)
    float whh1[KP], wih2[KP], whh2[KP];
#pragma unroll
    for (int k = 0; k < KP; ++k) {
        whh1[k] = (k < HID) ? W_hh1[jc * HID + k] : 0.0f;
        wih2[k] = (k < HID) ? W_ih2[jc * HID + k] : 0.0f;
        whh2[k] = (k < HID) ? W_hh2[jc * HID + k] : 0.0f;
    }
    const float wih1  = W_ih1[jc];
    const float bias1 = b_ih1[jc] + b_hh1[jc];
    const float bias2 = b_ih2[jc] + b_hh2[jc];

    // output-reduction weight (wave 0 lanes 0..50)
    const float wlin = (j < HID) ? W_lin[j] : 0.0f;
    const float blin = b_lin[0];

    // updater mapping: gate-position uj handled by thread (uj%4)*64 + uj/4
    const int uw = j >> 6;        // wave id
    const int ul = j & 63;        // lane id
    const int uj = uw + 4 * ul;   // hidden index this thread updates
    const bool is_upd = (ul < 13) && (uj < HID);

    float c1r = 0.0f, c2r = 0.0f;

    __syncthreads();

    const float4* h14 = reinterpret_cast<const float4*>(h1s);
    const float4* h24 = reinterpret_cast<const float4*>(h2s);

    for (int t = 0; t < OT; ++t) {
        // ---- layer-1 input ----
        float x = (t < TSEQ) ? input[b * TSEQ + t] : xs;

        // ---- layer-1 gate pre-activations ----
        float acc = bias1 + x * wih1;
#pragma unroll
        for (int cc = 0; cc < KP / 4; ++cc) {
            float4 hv = h14[cc];
            acc += hv.x * whh1[4 * cc + 0];
            acc += hv.y * whh1[4 * cc + 1];
            acc += hv.z * whh1[4 * cc + 2];
            acc += hv.w * whh1[4 * cc + 3];
        }
        if (j < G4) gs[j] = acc;
        __syncthreads();                       // A: gates1 ready

        // ---- layer-1 elementwise update ----
        if (is_upd) {
            float gi = gs[uj];
            float gf = gs[HID + uj];
            float gg = gs[2 * HID + uj];
            float go = gs[3 * HID + uj];
            c1r = sigf(gf) * c1r + sigf(gi) * tanhf_(gg);
            h1s[uj] = sigf(go) * tanhf_(c1r);
        }
        __syncthreads();                       // B: h1 ready

        // ---- layer-2 gate pre-activations ----
        float acc2 = bias2;
#pragma unroll
        for (int cc = 0; cc < KP / 4; ++cc) {
            float4 hv1 = h14[cc];
            acc2 += hv1.x * wih2[4 * cc + 0];
            acc2 += hv1.y * wih2[4 * cc + 1];
            acc2 += hv1.z * wih2[4 * cc + 2];
            acc2 += hv1.w * wih2[4 * cc + 3];
            float4 hv2 = h24[cc];
            acc2 += hv2.x * whh2[4 * cc + 0];
            acc2 += hv2.y * whh2[4 * cc + 1];
            acc2 += hv2.z * whh2[4 * cc + 2];
            acc2 += hv2.w * whh2[4 * cc + 3];
        }
        if (j < G4) gs[j] = acc2;
        __syncthreads();                       // C: gates2 ready

        // ---- layer-2 elementwise update ----
        if (is_upd) {
            float gi = gs[uj];
            float gf = gs[HID + uj];
            float gg = gs[2 * HID + uj];
            float go = gs[3 * HID + uj];
            c2r = sigf(gf) * c2r + sigf(gi) * tanhf_(gg);
            h2s[uj] = sigf(go) * tanhf_(c2r);
        }
        __syncthreads();                       // D: h2 ready

        // ---- output projection: wave 0 reduces dot(h2, W_lin) ----
        if (j < 64) {
            float v = (j < HID) ? h2s[j] * wlin : 0.0f;
            v += __shfl_down(v, 32);
            v += __shfl_down(v, 16);
            v += __shfl_down(v, 8);
            v += __shfl_down(v, 4);
            v += __shfl_down(v, 2);
            v += __shfl_down(v, 1);
            if (j == 0) {
                float o = v + blin;
                out[b * OT + t] = o;
                if (t >= TSEQ - 1) xs = o;     // feedback for autoregressive phase
            }
        }
        if (t >= TSEQ - 1) __syncthreads();    // E: xs visible before next read
    }
}

extern "C" void kernel_launch(void* const* d_in, const int* in_sizes, int n_in,
                              void* d_out, int out_size, void* d_ws, size_t ws_size,
                              hipStream_t stream) {
    const float* input = (const float*)d_in[0];
    const float* W_ih1 = (const float*)d_in[1];
    const float* W_hh1 = (const float*)d_in[2];
    const float* b_ih1 = (const float*)d_in[3];
    const float* b_hh1 = (const float*)d_in[4];
    const float* W_ih2 = (const float*)d_in[5];
    const float* W_hh2 = (const float*)d_in[6];
    const float* b_ih2 = (const float*)d_in[7];
    const float* b_hh2 = (const float*)d_in[8];
    const float* W_lin = (const float*)d_in[9];
    const float* b_lin = (const float*)d_in[10];

    const int bsz = in_sizes[0] / TSEQ;   // 4096

    hipLaunchKernelGGL(lstm_seq_kernel, dim3(bsz), dim3(256), 0, stream,
                       input, W_ih1, W_hh1, b_ih1, b_hh1,
                       W_ih2, W_hh2, b_ih2, b_hh2, W_lin, b_lin,
                       (float*)d_out);
}

// Round 2
// 1746.689 us; speedup vs baseline: 4.2744x; 4.2744x over previous
//
#include <hip/hip_runtime.h>

#define TSEQ 512
#define FUT  16
#define OT   (TSEQ + FUT)
#define NB   16          // batch rows per block (= MFMA M)

typedef _Float16 f16x8 __attribute__((ext_vector_type(8)));
typedef float    f32x4 __attribute__((ext_vector_type(4)));

__device__ __forceinline__ float sigf(float x) {
    return __builtin_amdgcn_rcpf(1.0f + __expf(-x));
}
__device__ __forceinline__ float tanhfast(float x) {
    return fmaf(2.0f, __builtin_amdgcn_rcpf(1.0f + __expf(-2.0f * x)), -1.0f);
}
__device__ __forceinline__ f32x4 mfma16(f16x8 a, f16x8 b, f32x4 c) {
    return __builtin_amdgcn_mfma_f32_16x16x32_f16(a, b, c, 0, 0, 0);
}
__device__ __forceinline__ _Float16 f16hi(float x) { return (_Float16)x; }
__device__ __forceinline__ _Float16 f16lo(float x, _Float16 hi) { return (_Float16)(x - (float)hi); }

// 4x4 transpose within each lane-quad + LSTM cell update.
// Pre: acc[r] = preact(batch 4q+r, gate' = 16t+n) (bias already folded in).
// Post: lane owns (m = 4q + (n&3), u = 4t + (n>>2)); c,h updated.
__device__ __forceinline__ void cell_update(const f32x4 acc, const int lq,
                                            float& c, float& h_out)
{
    float v[4] = {acc[0], acc[1], acc[2], acc[3]};
    float s1[4], g4[4];
#pragma unroll
    for (int r = 0; r < 4; ++r) {
        float pp = __shfl_xor(v[r ^ 1], 1, 64);
        s1[r] = (((lq ^ r) & 1) ? pp : v[r]);
    }
#pragma unroll
    for (int r = 0; r < 4; ++r) {
        float pp = __shfl_xor(s1[r ^ 2], 2, 64);
        g4[r] = (((lq ^ r) & 2) ? pp : s1[r]);
    }
    const float si = sigf(g4[0]);
    const float sf = sigf(g4[1]);
    const float tg = tanhfast(g4[2]);
    const float so = sigf(g4[3]);
    c = fmaf(sf, c, si * tg);
    h_out = so * tanhfast(c);
}

__global__ __launch_bounds__(256, 1) void lstm_mfma_kernel(
    const float* __restrict__ input,   // [B, 512]
    const float* __restrict__ W_ih1,   // [204,1]
    const float* __restrict__ W_hh1,   // [204,51]
    const float* __restrict__ b_ih1,
    const float* __restrict__ b_hh1,
    const float* __restrict__ W_ih2,   // [204,51]
    const float* __restrict__ W_hh2,   // [204,51]
    const float* __restrict__ b_ih2,
    const float* __restrict__ b_hh2,
    const float* __restrict__ W_lin,   // [1,51]
    const float* __restrict__ b_lin,
    float* __restrict__ out)           // [B, 528]
{
    const int tid  = threadIdx.x;
    const int w    = tid >> 6;
    const int lane = tid & 63;
    const int n    = lane & 15;   // MFMA m/n lane index
    const int q    = lane >> 4;   // k-group
    const int lq   = n & 3;       // lane-in-quad (gate type pre-transpose)
    const int mq   = 4 * q + lq;  // batch row owned post-transpose
    const int mu   = n >> 2;      // unit-in-tile owned post-transpose
    const int b0   = blockIdx.x * NB;

    // activation tiles in MFMA *fragment* layout, double-buffered by step parity.
    // index: [parity][kstep][lane][elem]; logical k = 32*kstep + 8*(lane>>4) + elem
    __shared__ _Float16 AhHi[2][2][64][8] __attribute__((aligned(16)));  // h1 | x(col 51)
    __shared__ _Float16 AhLo[2][2][64][8] __attribute__((aligned(16)));
    __shared__ _Float16 BhHi[2][2][64][8] __attribute__((aligned(16)));  // h2
    __shared__ _Float16 BhLo[2][2][64][8] __attribute__((aligned(16)));
    __shared__ float outbuf[16][4] __attribute__((aligned(16)));

    // 13 n-tiles of 16 gates (gate' = 4*u + gtype), split 4/3/3/3 across waves
    const int NT = (w == 0) ? 4 : 3;
    const int T0 = (w == 0) ? 0 : 3 * w + 1;

    // ---- preload weight fragments (f16 hi/lo split), biases, wlin ----
    f16x8 W1f[4][2][2];   // [tile][kstep][hi/lo]
    f16x8 W2f[4][4][2];
    float bias1_[4] = {0,0,0,0}, bias2_[4] = {0,0,0,0}, wlin_[4] = {0,0,0,0};
    int   u_[4], us_[4], lp_[4], ue_[4];

#pragma unroll
    for (int it = 0; it < 4; ++it) {
        const int tt = T0 + it;
        const int uu = 4 * tt + mu;
        u_[it]  = uu;
        us_[it] = uu >> 5;
        lp_[it] = mq + 16 * ((uu & 31) >> 3);
        ue_[it] = uu & 7;
        if (it < NT) {
            const int row = 51 * lq + (uu < 51 ? uu : 50);  // PyTorch row = 51*gtype + u
#pragma unroll
            for (int s = 0; s < 2; ++s) {
#pragma unroll
                for (int e = 0; e < 8; ++e) {
                    const int k = 32 * s + 8 * q + e;
                    float wv = 0.0f;
                    if (k < 51)       wv = W_hh1[row * 51 + k];
                    else if (k == 51) wv = W_ih1[row];       // x column
                    if (uu >= 51)     wv = 0.0f;             // pad unit
                    const _Float16 hi = f16hi(wv);
                    ((_Float16*)&W1f[it][s][0])[e] = hi;
                    ((_Float16*)&W1f[it][s][1])[e] = f16lo(wv, hi);
                }
            }
#pragma unroll
            for (int s = 0; s < 4; ++s) {
#pragma unroll
                for (int e = 0; e < 8; ++e) {
                    const int k = 32 * s + 8 * q + e;
                    float wv = 0.0f;
                    if (k < 51)                  wv = W_ih2[row * 51 + k];        // h1 block (x col 51 -> 0)
                    else if (k >= 64 && k < 115) wv = W_hh2[row * 51 + (k - 64)]; // h2 block
                    if (uu >= 51)                wv = 0.0f;
                    const _Float16 hi = f16hi(wv);
                    ((_Float16*)&W2f[it][s][0])[e] = hi;
                    ((_Float16*)&W2f[it][s][1])[e] = f16lo(wv, hi);
                }
            }
            bias1_[it] = b_ih1[row] + b_hh1[row];
            bias2_[it] = b_ih2[row] + b_hh2[row];
            wlin_[it]  = (uu < 51) ? W_lin[uu] : 0.0f;
        }
    }
    const float blin = b_lin[0];

    // ---- zero LDS, seed x0 ----
    {
        _Float16* p0 = &AhHi[0][0][0][0];
        _Float16* p1 = &AhLo[0][0][0][0];
        _Float16* p2 = &BhHi[0][0][0][0];
        _Float16* p3 = &BhLo[0][0][0][0];
        for (int i = tid; i < 2 * 2 * 64 * 8; i += 256) {
            p0[i] = (_Float16)0.0f; p1[i] = (_Float16)0.0f;
            p2[i] = (_Float16)0.0f; p3[i] = (_Float16)0.0f;
        }
    }
    __syncthreads();
    if (tid < NB) {   // x0 at logical col 51: kstep1, lane m+32, elem 3
        const float x0 = input[(b0 + tid) * TSEQ + 0];
        const _Float16 hi = f16hi(x0);
        AhHi[0][1][tid + 32][3] = hi;
        AhLo[0][1][tid + 32][3] = f16lo(x0, hi);
    }
    __syncthreads();

    float c1_[4] = {0,0,0,0}, c2_[4] = {0,0,0,0};

    for (int t = 0; t < OT; ++t) {
        const int p  = t & 1;
        const int pn = p ^ 1;

        // ---- P1: read current fragments (h1_{t-1}+x_t, h2_{t-1}) ----
        const f16x8 a0h = *(const f16x8*)&AhHi[p][0][lane][0];
        const f16x8 a1h = *(const f16x8*)&AhHi[p][1][lane][0];
        const f16x8 a0l = *(const f16x8*)&AhLo[p][0][lane][0];
        const f16x8 a1l = *(const f16x8*)&AhLo[p][1][lane][0];
        const f16x8 b0h = *(const f16x8*)&BhHi[p][0][lane][0];
        const f16x8 b1h = *(const f16x8*)&BhHi[p][1][lane][0];
        const f16x8 b0l = *(const f16x8*)&BhLo[p][0][lane][0];
        const f16x8 b1l = *(const f16x8*)&BhLo[p][1][lane][0];

        // ---- P2: layer-1 gates (3-term f16 split) + update -> write h1_t into alt buffer ----
        f32x4 acc[4];
#pragma unroll
        for (int it = 0; it < 4; ++it) {
            if (it < NT) {
                acc[it] = (f32x4){bias1_[it], bias1_[it], bias1_[it], bias1_[it]};
                acc[it] = mfma16(a0h, W1f[it][0][0], acc[it]);
                acc[it] = mfma16(a0l, W1f[it][0][0], acc[it]);
                acc[it] = mfma16(a0h, W1f[it][0][1], acc[it]);
                acc[it] = mfma16(a1h, W1f[it][1][0], acc[it]);
                acc[it] = mfma16(a1l, W1f[it][1][0], acc[it]);
                acc[it] = mfma16(a1h, W1f[it][1][1], acc[it]);
            }
        }
#pragma unroll
        for (int it = 0; it < 4; ++it) {
            if (it < NT) {
                float h;
                cell_update(acc[it], lq, c1_[it], h);
                if (u_[it] < 51) {
                    const _Float16 hi = f16hi(h);
                    AhHi[pn][us_[it]][lp_[it]][ue_[it]] = hi;
                    AhLo[pn][us_[it]][lp_[it]][ue_[it]] = f16lo(h, hi);
                }
            }
        }
        __syncthreads();   // BAR-A: h1_t visible

        // ---- P3: layer-2 gates + update -> write h2_t; out partials ----
        const f16x8 n0h = *(const f16x8*)&AhHi[pn][0][lane][0];
        const f16x8 n1h = *(const f16x8*)&AhHi[pn][1][lane][0];
        const f16x8 n0l = *(const f16x8*)&AhLo[pn][0][lane][0];
        const f16x8 n1l = *(const f16x8*)&AhLo[pn][1][lane][0];
#pragma unroll
        for (int it = 0; it < 4; ++it) {
            if (it < NT) {
                acc[it] = (f32x4){bias2_[it], bias2_[it], bias2_[it], bias2_[it]};
                acc[it] = mfma16(n0h, W2f[it][0][0], acc[it]);
                acc[it] = mfma16(n0l, W2f[it][0][0], acc[it]);
                acc[it] = mfma16(n0h, W2f[it][0][1], acc[it]);
                acc[it] = mfma16(n1h, W2f[it][1][0], acc[it]);
                acc[it] = mfma16(n1l, W2f[it][1][0], acc[it]);
                acc[it] = mfma16(n1h, W2f[it][1][1], acc[it]);
                acc[it] = mfma16(b0h, W2f[it][2][0], acc[it]);
                acc[it] = mfma16(b0l, W2f[it][2][0], acc[it]);
                acc[it] = mfma16(b0h, W2f[it][2][1], acc[it]);
                acc[it] = mfma16(b1h, W2f[it][3][0], acc[it]);
                acc[it] = mfma16(b1l, W2f[it][3][0], acc[it]);
                acc[it] = mfma16(b1h, W2f[it][3][1], acc[it]);
            }
        }
        float po = 0.0f;
#pragma unroll
        for (int it = 0; it < 4; ++it) {
            if (it < NT) {
                float h;
                cell_update(acc[it], lq, c2_[it], h);
                po = fmaf(h, wlin_[it], po);
                if (u_[it] < 51) {
                    const _Float16 hi = f16hi(h);
                    BhHi[pn][us_[it]][lp_[it]][ue_[it]] = hi;
                    BhLo[pn][us_[it]][lp_[it]][ue_[it]] = f16lo(h, hi);
                }
            }
        }
        po += __shfl_xor(po, 4, 64);
        po += __shfl_xor(po, 8, 64);
        if ((lane & 12) == 0) outbuf[mq][w] = po;
        __syncthreads();   // BAR-B: h2_t + out partials visible

        // ---- P4: finalize out; stage next x into alt buffer's col 51 ----
        if (w == 0) {
            if (lane < NB) {
                const int m = lane;
                const float o = outbuf[m][0] + outbuf[m][1] + outbuf[m][2] + outbuf[m][3] + blin;
                out[(b0 + m) * OT + t] = o;
                if (t >= TSEQ - 1 && t < OT - 1) {   // autoregressive feedback
                    const _Float16 hi = f16hi(o);
                    AhHi[pn][1][m + 32][3] = hi;
                    AhLo[pn][1][m + 32][3] = f16lo(o, hi);
                }
            } else if (lane < 2 * NB && (t + 1) < TSEQ) {
                const int m = lane - NB;
                const float xn = input[(b0 + m) * TSEQ + t + 1];
                const _Float16 hi = f16hi(xn);
                AhHi[pn][1][m + 32][3] = hi;
                AhLo[pn][1][m + 32][3] = f16lo(xn, hi);
            }
        }
        __syncthreads();   // BAR-C: next step may read alt buffers
    }
}

extern "C" void kernel_launch(void* const* d_in, const int* in_sizes, int n_in,
                              void* d_out, int out_size, void* d_ws, size_t ws_size,
                              hipStream_t stream) {
    const float* input = (const float*)d_in[0];
    const float* W_ih1 = (const float*)d_in[1];
    const float* W_hh1 = (const float*)d_in[2];
    const float* b_ih1 = (const float*)d_in[3];
    const float* b_hh1 = (const float*)d_in[4];
    const float* W_ih2 = (const float*)d_in[5];
    const float* W_hh2 = (const float*)d_in[6];
    const float* b_ih2 = (const float*)d_in[7];
    const float* b_hh2 = (const float*)d_in[8];
    const float* W_lin = (const float*)d_in[9];
    const float* b_lin = (const float*)d_in[10];

    const int bsz = in_sizes[0] / TSEQ;   // 4096

    hipLaunchKernelGGL(lstm_mfma_kernel, dim3(bsz / NB), dim3(256), 0, stream,
                       input, W_ih1, W_hh1, b_ih1, b_hh1,
                       W_ih2, W_hh2, b_ih2, b_hh2, W_lin, b_lin,
                       (float*)d_out);
}

// Round 3
// 797.748 us; speedup vs baseline: 9.3589x; 2.1895x over previous
//
#include <hip/hip_runtime.h>

#define TSEQ 512
#define FUT  16
#define OT   (TSEQ + FUT)
#define NB   16          // batch rows per block (= MFMA M)
#define NWAVE 13
#define NTHREADS (NWAVE * 64)

typedef _Float16 f16x8 __attribute__((ext_vector_type(8)));
typedef float    f32x4 __attribute__((ext_vector_type(4)));

__device__ __forceinline__ float sigf(float x) {
    return __builtin_amdgcn_rcpf(1.0f + __expf(-x));
}
__device__ __forceinline__ float tanhfast(float x) {
    return fmaf(2.0f, __builtin_amdgcn_rcpf(1.0f + __expf(-2.0f * x)), -1.0f);
}
__device__ __forceinline__ f32x4 mfma16(f16x8 a, f16x8 b, f32x4 c) {
    return __builtin_amdgcn_mfma_f32_16x16x32_f16(a, b, c, 0, 0, 0);
}
// quad_perm DPP lane swaps: xor1 -> [1,0,3,2]=0xB1, xor2 -> [2,3,0,1]=0x4E
__device__ __forceinline__ float dpp_x1(float x) {
    return __builtin_bit_cast(float,
        __builtin_amdgcn_update_dpp(0, __builtin_bit_cast(int, x), 0xB1, 0xF, 0xF, true));
}
__device__ __forceinline__ float dpp_x2(float x) {
    return __builtin_bit_cast(float,
        __builtin_amdgcn_update_dpp(0, __builtin_bit_cast(int, x), 0x4E, 0xF, 0xF, true));
}

// 4x4 transpose within each lane-quad (pure-VALU DPP) + LSTM cell update.
// Pre: acc[r] = preact(batch 4q+r, gate' = 16w+n), bias folded in.
// Post: lane owns (m = 4q+(n&3), u = 4w+(n>>2)); c updated, h_out produced.
__device__ __forceinline__ void cell_update(const f32x4 acc, const int lq,
                                            float& c, float& h_out)
{
    float v[4] = {acc[0], acc[1], acc[2], acc[3]};
    float s1[4], g4[4];
#pragma unroll
    for (int r = 0; r < 4; ++r) {
        float pp = dpp_x1(v[r ^ 1]);
        s1[r] = (((lq ^ r) & 1) ? pp : v[r]);
    }
#pragma unroll
    for (int r = 0; r < 4; ++r) {
        float pp = dpp_x2(s1[r ^ 2]);
        g4[r] = (((lq ^ r) & 2) ? pp : s1[r]);
    }
    const float si = sigf(g4[0]);
    const float sf = sigf(g4[1]);
    const float tg = tanhfast(g4[2]);
    const float so = sigf(g4[3]);
    c = fmaf(sf, c, si * tg);
    h_out = so * tanhfast(c);
}

__global__ __launch_bounds__(NTHREADS, 1) void lstm_mfma_kernel(
    const float* __restrict__ input,   // [B, 512]
    const float* __restrict__ W_ih1,   // [204,1]
    const float* __restrict__ W_hh1,   // [204,51]
    const float* __restrict__ b_ih1,
    const float* __restrict__ b_hh1,
    const float* __restrict__ W_ih2,   // [204,51]
    const float* __restrict__ W_hh2,   // [204,51]
    const float* __restrict__ b_ih2,
    const float* __restrict__ b_hh2,
    const float* __restrict__ W_lin,   // [1,51]
    const float* __restrict__ b_lin,
    float* __restrict__ out)           // [B, 528]
{
    const int tid  = threadIdx.x;
    const int w    = tid >> 6;    // wave id = tile id (0..12)
    const int lane = tid & 63;
    const int n    = lane & 15;   // MFMA m/n lane index
    const int q    = lane >> 4;   // k-group
    const int lq   = n & 3;       // lane-in-quad (gate type pre-transpose)
    const int mq   = 4 * q + lq;  // batch row owned post-transpose
    const int mu   = n >> 2;      // unit-in-tile owned post-transpose
    const int b0   = blockIdx.x * NB;

    // HB[arr][parity][kstep][lane][elem]; arr: 0=h1 hi, 1=h1 lo, 2=h2 hi, 3=h2 lo
    // fragment layout: logical k stored at [k>>5][m + 16*((k&31)>>3)][k&7]
    __shared__ _Float16 HB[4][2][2][64][8] __attribute__((aligned(16)));
    __shared__ float outbuf[16][16] __attribute__((aligned(16)));

    const int uu = 4 * w + mu;          // unit this lane updates
    const int us = uu >> 5;
    const int ue = uu & 7;
    const int lp = mq + 16 * ((uu & 31) >> 3);
    const bool ustore = (uu < 51);

    // ---- per-wave weight fragments (f16 hi/lo split) ----
    f16x8 W1f[2][2];   // [kstep][hi/lo] over k = h1(0..50) | x(51)
    f16x8 W2f[4][2];   // [kstep][hi/lo] over k = h1(0..50) | pad | h2(64..114)
    const int row = 51 * lq + (uu < 51 ? uu : 50);  // PyTorch row = 51*gtype + u
#pragma unroll
    for (int s = 0; s < 2; ++s) {
#pragma unroll
        for (int e = 0; e < 8; ++e) {
            const int k = 32 * s + 8 * q + e;
            float wv = 0.0f;
            if (uu < 51) {
                if (k < 51)       wv = W_hh1[row * 51 + k];
                else if (k == 51) wv = W_ih1[row];
            }
            const _Float16 hi = (_Float16)wv;
            ((_Float16*)&W1f[s][0])[e] = hi;
            ((_Float16*)&W1f[s][1])[e] = (_Float16)(wv - (float)hi);
        }
    }
#pragma unroll
    for (int s = 0; s < 4; ++s) {
#pragma unroll
        for (int e = 0; e < 8; ++e) {
            const int k = 32 * s + 8 * q + e;
            float wv = 0.0f;
            if (uu < 51) {
                if (k < 51)                  wv = W_ih2[row * 51 + k];
                else if (k >= 64 && k < 115) wv = W_hh2[row * 51 + (k - 64)];
            }
            const _Float16 hi = (_Float16)wv;
            ((_Float16*)&W2f[s][0])[e] = hi;
            ((_Float16*)&W2f[s][1])[e] = (_Float16)(wv - (float)hi);
        }
    }
    const float bias1 = (uu < 51) ? (b_ih1[row] + b_hh1[row]) : 0.0f;
    const float bias2 = (uu < 51) ? (b_ih2[row] + b_hh2[row]) : 0.0f;
    const float wlin  = (uu < 51) ? W_lin[uu] : 0.0f;
    const float blin  = b_lin[0];

    // ---- zero activation LDS (both parities; cols >= 51 stay 0 forever) ----
    {
        const f16x8 zz = {0, 0, 0, 0, 0, 0, 0, 0};
        f16x8* hb = (f16x8*)&HB[0][0][0][0][0];
        for (int i = tid; i < 4 * 2 * 2 * 64; i += NTHREADS) hb[i] = zz;
    }
    __syncthreads();

    float c1 = 0.0f, c2 = 0.0f;
    float xcur = 0.0f;
    if (q == 2) xcur = input[(b0 + n) * TSEQ + 0];   // lane 32+m holds x for batch m

    for (int t = 0; t < OT; ++t) {
        const int p  = t & 1;
        const int pn = p ^ 1;

        // prefetch next input (hidden under this step's compute)
        float xnxt = 0.0f;
        if (q == 2 && (t + 1) < TSEQ) xnxt = input[(b0 + n) * TSEQ + (t + 1)];

        // ---- L1: A-frags = h1_{t-1} (+ x_t patched at logical col 51) ----
        f16x8 a0h = *(const f16x8*)&HB[0][p][0][lane][0];
        f16x8 a1h = *(const f16x8*)&HB[0][p][1][lane][0];
        f16x8 a0l = *(const f16x8*)&HB[1][p][0][lane][0];
        f16x8 a1l = *(const f16x8*)&HB[1][p][1][lane][0];
        if (q == 2) {   // col 51 = kstep1, kgroup2, elem3
            const _Float16 hi = (_Float16)xcur;
            a1h[3] = hi;
            a1l[3] = (_Float16)(xcur - (float)hi);
        }
        f32x4 acc = {bias1, bias1, bias1, bias1};
        acc = mfma16(a0h, W1f[0][0], acc);
        acc = mfma16(a0l, W1f[0][0], acc);
        acc = mfma16(a0h, W1f[0][1], acc);
        acc = mfma16(a1h, W1f[1][0], acc);
        acc = mfma16(a1l, W1f[1][0], acc);
        acc = mfma16(a1h, W1f[1][1], acc);

        float h1n;
        cell_update(acc, lq, c1, h1n);
        if (ustore) {
            const _Float16 hi = (_Float16)h1n;
            HB[0][pn][us][lp][ue] = hi;
            HB[1][pn][us][lp][ue] = (_Float16)(h1n - (float)hi);
        }
        __syncthreads();   // BAR-A: h1_t visible

        // ---- L2: A = [h1_t | pad | h2_{t-1}] ----
        f16x8 n0h = *(const f16x8*)&HB[0][pn][0][lane][0];
        f16x8 n1h = *(const f16x8*)&HB[0][pn][1][lane][0];
        f16x8 n0l = *(const f16x8*)&HB[1][pn][0][lane][0];
        f16x8 n1l = *(const f16x8*)&HB[1][pn][1][lane][0];
        f16x8 b0h = *(const f16x8*)&HB[2][p][0][lane][0];
        f16x8 b1h = *(const f16x8*)&HB[2][p][1][lane][0];
        f16x8 b0l = *(const f16x8*)&HB[3][p][0][lane][0];
        f16x8 b1l = *(const f16x8*)&HB[3][p][1][lane][0];

        f32x4 ac2 = {bias2, bias2, bias2, bias2};
        ac2 = mfma16(n0h, W2f[0][0], ac2);
        ac2 = mfma16(n0l, W2f[0][0], ac2);
        ac2 = mfma16(n0h, W2f[0][1], ac2);
        ac2 = mfma16(n1h, W2f[1][0], ac2);
        ac2 = mfma16(n1l, W2f[1][0], ac2);
        ac2 = mfma16(n1h, W2f[1][1], ac2);
        ac2 = mfma16(b0h, W2f[2][0], ac2);
        ac2 = mfma16(b0l, W2f[2][0], ac2);
        ac2 = mfma16(b0h, W2f[2][1], ac2);
        ac2 = mfma16(b1h, W2f[3][0], ac2);
        ac2 = mfma16(b1l, W2f[3][0], ac2);
        ac2 = mfma16(b1h, W2f[3][1], ac2);

        float h2n;
        cell_update(ac2, lq, c2, h2n);
        if (ustore) {
            const _Float16 hi = (_Float16)h2n;
            HB[2][pn][us][lp][ue] = hi;
            HB[3][pn][us][lp][ue] = (_Float16)(h2n - (float)hi);
        }
        // out partial: reduce over the 4 units of this tile (lanes differing in n bits 2-3)
        float po = h2n * wlin;
        po += __shfl_xor(po, 4, 64);
        po += __shfl_xor(po, 8, 64);
        if ((lane & 12) == 0) outbuf[mq][w] = po;
        __syncthreads();   // BAR-B: h2_t + out partials visible

        // ---- finalize: o = sum of 13 wave partials + blin ----
        // store duty: wave 3 lanes 0-15; feedback duty: lanes 32-47 (q==2) of all waves
        const bool fb = (q == 2) && (t >= TSEQ - 1);
        if ((w == 3 && lane < 16) || fb) {
            const int m = (lane < 16) ? lane : n;
            const f32x4* ob = (const f32x4*)&outbuf[m][0];
            const f32x4 s0 = ob[0], s1v = ob[1], s2v = ob[2];
            const float o = ((s0[0] + s0[1]) + (s0[2] + s0[3]))
                          + ((s1v[0] + s1v[1]) + (s1v[2] + s1v[3]))
                          + ((s2v[0] + s2v[1]) + (s2v[2] + s2v[3]))
                          + outbuf[m][12] + blin;
            if (w == 3 && lane < 16) out[(b0 + m) * OT + t] = o;
            if (fb) xnxt = o;                 // autoregressive feedback
        }
        xcur = xnxt;
        // WAR safety: outbuf/frag rewrites for t+1 happen only after BAR-A(t+1),
        // which every wave reaches after completing the reads above.
    }
}

extern "C" void kernel_launch(void* const* d_in, const int* in_sizes, int n_in,
                              void* d_out, int out_size, void* d_ws, size_t ws_size,
                              hipStream_t stream) {
    const float* input = (const float*)d_in[0];
    const float* W_ih1 = (const float*)d_in[1];
    const float* W_hh1 = (const float*)d_in[2];
    const float* b_ih1 = (const float*)d_in[3];
    const float* b_hh1 = (const float*)d_in[4];
    const float* W_ih2 = (const float*)d_in[5];
    const float* W_hh2 = (const float*)d_in[6];
    const float* b_ih2 = (const float*)d_in[7];
    const float* b_hh2 = (const float*)d_in[8];
    const float* W_lin = (const float*)d_in[9];
    const float* b_lin = (const float*)d_in[10];

    const int bsz = in_sizes[0] / TSEQ;   // 4096

    hipLaunchKernelGGL(lstm_mfma_kernel, dim3(bsz / NB), dim3(NTHREADS), 0, stream,
                       input, W_ih1, W_hh1, b_ih1, b_hh1,
                       W_ih2, W_hh2, b_ih2, b_hh2, W_lin, b_lin,
                       (float*)d_out);
}

// Round 4
// 534.108 us; speedup vs baseline: 13.9785x; 1.4936x over previous
//
#include <hip/hip_runtime.h>

#define TSEQ 512
#define FUT  16
#define OT   (TSEQ + FUT)
#define NB   16
#define NWAVE 13
#define NTHREADS (NWAVE * 64)
#define OBS  20   // outbuf row stride in floats (16B-aligned rows, 2-way-free banks)

typedef _Float16 f16x8 __attribute__((ext_vector_type(8)));
typedef float    f32x4 __attribute__((ext_vector_type(4)));

__device__ __forceinline__ float sigf(float x) {
    return __builtin_amdgcn_rcpf(1.0f + __expf(-x));
}
__device__ __forceinline__ float tanhfast(float x) {
    return fmaf(2.0f, __builtin_amdgcn_rcpf(1.0f + __expf(-2.0f * x)), -1.0f);
}
__device__ __forceinline__ f32x4 mfma16(f16x8 a, f16x8 b, f32x4 c) {
    return __builtin_amdgcn_mfma_f32_16x16x32_f16(a, b, c, 0, 0, 0);
}
// acc regs are (i,f,g,o) for this lane's (batch, unit) -- no transpose needed
__device__ __forceinline__ float cell2(const f32x4 acc, float& c) {
    const float si = sigf(acc[0]);
    const float sf = sigf(acc[1]);
    const float tg = tanhfast(acc[2]);
    const float so = sigf(acc[3]);
    c = fmaf(sf, c, si * tg);
    return so * tanhfast(c);
}

__global__ __launch_bounds__(NTHREADS, 1) void lstm_mfma_kernel(
    const float* __restrict__ input,   // [B, 512]
    const float* __restrict__ W_ih1,   // [204,1]
    const float* __restrict__ W_hh1,   // [204,51]
    const float* __restrict__ b_ih1,
    const float* __restrict__ b_hh1,
    const float* __restrict__ W_ih2,   // [204,51]
    const float* __restrict__ W_hh2,   // [204,51]
    const float* __restrict__ b_ih2,
    const float* __restrict__ b_hh2,
    const float* __restrict__ W_lin,   // [1,51]
    const float* __restrict__ b_lin,
    float* __restrict__ out)           // [B, 528]
{
    const int tid  = threadIdx.x;
    const int w    = tid >> 6;    // wave id = gate-tile id (0..12)
    const int lane = tid & 63;
    const int n    = lane & 15;   // batch col (B operand) / A row index
    const int q    = lane >> 4;   // k-group; also unit-in-tile this lane updates
    const int b0   = blockIdx.x * NB;

    // activations (hi-only f16) in MFMA B-fragment layout, parity double-buffered
    // logical k stored at [k>>5][n + 16*((k&31)>>3)][k&7]
    __shared__ _Float16 H1[2][2][64][8] __attribute__((aligned(16)));
    __shared__ _Float16 H2[2][2][64][8] __attribute__((aligned(16)));
    __shared__ float OB[2][16][OBS] __attribute__((aligned(16)));

    // ---- A-operand (weights) fragments: lane holds A row m = n ----
    const int ru  = 4 * w + (n >> 2);              // unit of this A row
    const bool rv = (ru < 51);
    const int R   = 51 * (n & 3) + (rv ? ru : 50); // PyTorch row = 51*gtype + unit
    f16x8 W1h[2], W1l[2], W2h[4], W2l[4];
#pragma unroll
    for (int s = 0; s < 2; ++s) {
#pragma unroll
        for (int e = 0; e < 8; ++e) {
            const int k = 32 * s + 8 * q + e;
            float wv = 0.0f;
            if (rv) {
                if (k < 51)       wv = W_hh1[R * 51 + k];
                else if (k == 51) wv = W_ih1[R];        // x column
            }
            const _Float16 hi = (_Float16)wv;
            W1h[s][e] = hi;
            W1l[s][e] = (_Float16)(wv - (float)hi);
        }
    }
#pragma unroll
    for (int s = 0; s < 4; ++s) {
#pragma unroll
        for (int e = 0; e < 8; ++e) {
            const int k = 32 * s + 8 * q + e;
            float wv = 0.0f;
            if (rv) {
                if (k < 51)                  wv = W_ih2[R * 51 + k];        // h1 block
                else if (k >= 64 && k < 115) wv = W_hh2[R * 51 + (k - 64)]; // h2 block
            }
            const _Float16 hi = (_Float16)wv;
            W2h[s][e] = hi;
            W2l[s][e] = (_Float16)(wv - (float)hi);
        }
    }

    // ---- update-side constants: this lane updates (batch n, unit uu=4w+q) ----
    const int uu = 4 * w + q;
    const bool ustore = (uu < 51);
    f32x4 bias1v, bias2v;
#pragma unroll
    for (int r = 0; r < 4; ++r) {
        const int row = 51 * r + (ustore ? uu : 50);
        bias1v[r] = ustore ? (b_ih1[row] + b_hh1[row]) : 0.0f;
        bias2v[r] = ustore ? (b_ih2[row] + b_hh2[row]) : 0.0f;
    }
    const float wlin = ustore ? W_lin[uu] : 0.0f;
    const float blin = b_lin[0];
    const int us = uu >> 5;              // kstep of h store
    const int lp = n + 16 * ((uu & 31) >> 3);
    const int ue = uu & 7;

    // ---- zero activation LDS (both parities; pad cols stay 0 forever) ----
    {
        const f16x8 zz = {0, 0, 0, 0, 0, 0, 0, 0};
        f16x8* p1 = (f16x8*)&H1[0][0][0][0];
        f16x8* p2 = (f16x8*)&H2[0][0][0][0];
        for (int i = tid; i < 2 * 2 * 64; i += NTHREADS) { p1[i] = zz; p2[i] = zz; }
    }
    __syncthreads();

    float c1 = 0.0f, c2 = 0.0f;
    float xcur = 0.0f;
    if (q == 2) xcur = input[(b0 + n) * TSEQ + 0];

    // ---- prologue: phase 0 = L1(0) (h1_{-1}=0 -> only bias + x terms) ----
    {
        f16x8 xk1 = {0,0,0,0,0,0,0,0}, xlo = {0,0,0,0,0,0,0,0};
        if (q == 2) {
            const _Float16 hi = (_Float16)xcur;
            xk1[3] = hi;
            xlo[3] = (_Float16)(xcur - (float)hi);
        }
        f32x4 a1 = mfma16(W1h[1], xk1, bias1v);
        a1 = mfma16(W1l[1], xk1, a1);
        a1 = mfma16(W1h[1], xlo, a1);
        float h1n = cell2(a1, c1);
        if (ustore) H1[1][us][lp][ue] = (_Float16)h1n;   // h1_0 -> buf[1]
        if (q == 2) xcur = input[(b0 + n) * TSEQ + 1];   // x_1
    }
    __syncthreads();

    // ---- main pipelined loop: phase t does L1(t) || L2(t-1), 1 barrier ----
#pragma unroll 2
    for (int t = 1; t < TSEQ; ++t) {
        const int p  = t & 1;
        const int pn = p ^ 1;

        float xnxt = 0.0f;
        if (q == 2 && (t + 1) < TSEQ) xnxt = input[(b0 + n) * TSEQ + (t + 1)];

        // finalize o_{t-2} (wave 3) from partials written in phase t-1
        if (w == 3 && lane < 16 && t >= 2) {
            const float* ob = &OB[pn][lane][0];
            const f32x4 s0 = *(const f32x4*)&ob[0];
            const f32x4 s1 = *(const f32x4*)&ob[4];
            const f32x4 s2 = *(const f32x4*)&ob[8];
            const float o = ((s0[0] + s0[1]) + (s0[2] + s0[3]))
                          + ((s1[0] + s1[1]) + (s1[2] + s1[3]))
                          + ((s2[0] + s2[1]) + (s2[2] + s2[3]))
                          + ob[12] + blin;
            out[(b0 + lane) * OT + (t - 2)] = o;
        }

        // read fragments: h1_{t-1} (shared by L1 and L2), h2_{t-2}
        f16x8 h1k0 = *(const f16x8*)&H1[p][0][lane][0];
        f16x8 h1k1 = *(const f16x8*)&H1[p][1][lane][0];
        const f16x8 h2k0 = *(const f16x8*)&H2[p][0][lane][0];
        const f16x8 h2k1 = *(const f16x8*)&H2[p][1][lane][0];
        f16x8 xlo = {0,0,0,0,0,0,0,0};
        if (q == 2) {   // patch x_t at logical col 51 (W2 col 51 == 0, harmless for L2)
            const _Float16 hi = (_Float16)xcur;
            h1k1[3] = hi;
            xlo[3]  = (_Float16)(xcur - (float)hi);
        }

        // L1(t): gates1 = W1 * [h1_{t-1} | x_t]
        f32x4 a1 = mfma16(W1h[0], h1k0, bias1v);
        a1 = mfma16(W1l[0], h1k0, a1);
        a1 = mfma16(W1h[1], h1k1, a1);
        a1 = mfma16(W1l[1], h1k1, a1);
        a1 = mfma16(W1h[1], xlo,  a1);   // x lo-precision term

        // L2(t-1): gates2 = W2 * [h1_{t-1} | h2_{t-2}]
        f32x4 a2 = mfma16(W2h[0], h1k0, bias2v);
        a2 = mfma16(W2l[0], h1k0, a2);
        a2 = mfma16(W2h[1], h1k1, a2);
        a2 = mfma16(W2l[1], h1k1, a2);
        a2 = mfma16(W2h[2], h2k0, a2);
        a2 = mfma16(W2l[2], h2k0, a2);
        a2 = mfma16(W2h[3], h2k1, a2);
        a2 = mfma16(W2l[3], h2k1, a2);

        const float h1n = cell2(a1, c1);   // h1_t
        const float h2n = cell2(a2, c2);   // h2_{t-1}
        if (ustore) {
            H1[pn][us][lp][ue] = (_Float16)h1n;
            H2[pn][us][lp][ue] = (_Float16)h2n;
        }
        // output partials for o_{t-1}
        float po = h2n * wlin;
        po += __shfl_xor(po, 16, 64);
        po += __shfl_xor(po, 32, 64);
        if (lane < 16) OB[p][lane][w] = po;
        __syncthreads();
        xcur = xnxt;
    }

    // ---- tail: autoregressive steps t = 512..527 (x_t = o_{t-1}), 2 phases ----
    for (int t = TSEQ; t < OT; ++t) {
        const int p  = t & 1;
        const int pn = p ^ 1;

        // .a: L2(t-1)
        f16x8 h1k0 = *(const f16x8*)&H1[p][0][lane][0];
        f16x8 h1k1 = *(const f16x8*)&H1[p][1][lane][0];
        const f16x8 h2k0 = *(const f16x8*)&H2[p][0][lane][0];
        const f16x8 h2k1 = *(const f16x8*)&H2[p][1][lane][0];
        f32x4 a2 = mfma16(W2h[0], h1k0, bias2v);
        a2 = mfma16(W2l[0], h1k0, a2);
        a2 = mfma16(W2h[1], h1k1, a2);
        a2 = mfma16(W2l[1], h1k1, a2);
        a2 = mfma16(W2h[2], h2k0, a2);
        a2 = mfma16(W2l[2], h2k0, a2);
        a2 = mfma16(W2h[3], h2k1, a2);
        a2 = mfma16(W2l[3], h2k1, a2);
        const float h2n = cell2(a2, c2);
        if (ustore) H2[pn][us][lp][ue] = (_Float16)h2n;
        float po = h2n * wlin;
        po += __shfl_xor(po, 16, 64);
        po += __shfl_xor(po, 32, 64);
        if (lane < 16) OB[p][lane][w] = po;
        if (t == TSEQ && w == 3 && lane < 16) {   // pending o_{510} from main loop
            const float* ob = &OB[pn][lane][0];
            const f32x4 s0 = *(const f32x4*)&ob[0];
            const f32x4 s1 = *(const f32x4*)&ob[4];
            const f32x4 s2 = *(const f32x4*)&ob[8];
            out[(b0 + lane) * OT + (t - 2)] =
                ((s0[0] + s0[1]) + (s0[2] + s0[3])) +
                ((s1[0] + s1[1]) + (s1[2] + s1[3])) +
                ((s2[0] + s2[1]) + (s2[2] + s2[3])) + ob[12] + blin;
        }
        __syncthreads();

        // .b: finalize o_{t-1}; x_t = o_{t-1}; L1(t)
        const bool fin = (w == 3 && lane < 16) || (q == 2);
        float o = 0.0f;
        if (fin) {
            const int m = (lane < 16) ? lane : n;
            const float* ob = &OB[p][m][0];
            const f32x4 s0 = *(const f32x4*)&ob[0];
            const f32x4 s1 = *(const f32x4*)&ob[4];
            const f32x4 s2 = *(const f32x4*)&ob[8];
            o = ((s0[0] + s0[1]) + (s0[2] + s0[3]))
              + ((s1[0] + s1[1]) + (s1[2] + s1[3]))
              + ((s2[0] + s2[1]) + (s2[2] + s2[3])) + ob[12] + blin;
            if (w == 3 && lane < 16) out[(b0 + m) * OT + (t - 1)] = o;
        }
        f16x8 xlo = {0,0,0,0,0,0,0,0};
        if (q == 2) {
            xcur = o;
            const _Float16 hi = (_Float16)xcur;
            h1k1[3] = hi;
            xlo[3]  = (_Float16)(xcur - (float)hi);
        }
        f32x4 a1 = mfma16(W1h[0], h1k0, bias1v);
        a1 = mfma16(W1l[0], h1k0, a1);
        a1 = mfma16(W1h[1], h1k1, a1);
        a1 = mfma16(W1l[1], h1k1, a1);
        a1 = mfma16(W1h[1], xlo,  a1);
        const float h1n = cell2(a1, c1);
        if (ustore) H1[pn][us][lp][ue] = (_Float16)h1n;
        __syncthreads();
    }

    // ---- final phase: L2(527) + store o_527 ----
    {
        const f16x8 h1k0 = *(const f16x8*)&H1[0][0][lane][0];
        const f16x8 h1k1 = *(const f16x8*)&H1[0][1][lane][0];
        const f16x8 h2k0 = *(const f16x8*)&H2[0][0][lane][0];
        const f16x8 h2k1 = *(const f16x8*)&H2[0][1][lane][0];
        f32x4 a2 = mfma16(W2h[0], h1k0, bias2v);
        a2 = mfma16(W2l[0], h1k0, a2);
        a2 = mfma16(W2h[1], h1k1, a2);
        a2 = mfma16(W2l[1], h1k1, a2);
        a2 = mfma16(W2h[2], h2k0, a2);
        a2 = mfma16(W2l[2], h2k0, a2);
        a2 = mfma16(W2h[3], h2k1, a2);
        a2 = mfma16(W2l[3], h2k1, a2);
        const float h2n = cell2(a2, c2);
        float po = h2n * wlin;
        po += __shfl_xor(po, 16, 64);
        po += __shfl_xor(po, 32, 64);
        if (lane < 16) OB[0][lane][w] = po;
        __syncthreads();
        if (w == 3 && lane < 16) {
            const float* ob = &OB[0][lane][0];
            const f32x4 s0 = *(const f32x4*)&ob[0];
            const f32x4 s1 = *(const f32x4*)&ob[4];
            const f32x4 s2 = *(const f32x4*)&ob[8];
            out[(b0 + lane) * OT + (OT - 1)] =
                ((s0[0] + s0[1]) + (s0[2] + s0[3])) +
                ((s1[0] + s1[1]) + (s1[2] + s1[3])) +
                ((s2[0] + s2[1]) + (s2[2] + s2[3])) + ob[12] + blin;
        }
    }
}

extern "C" void kernel_launch(void* const* d_in, const int* in_sizes, int n_in,
                              void* d_out, int out_size, void* d_ws, size_t ws_size,
                              hipStream_t stream) {
    const float* input = (const float*)d_in[0];
    const float* W_ih1 = (const float*)d_in[1];
    const float* W_hh1 = (const float*)d_in[2];
    const float* b_ih1 = (const float*)d_in[3];
    const float* b_hh1 = (const float*)d_in[4];
    const float* W_ih2 = (const float*)d_in[5];
    const float* W_hh2 = (const float*)d_in[6];
    const float* b_ih2 = (const float*)d_in[7];
    const float* b_hh2 = (const float*)d_in[8];
    const float* W_lin = (const float*)d_in[9];
    const float* b_lin = (const float*)d_in[10];

    const int bsz = in_sizes[0] / TSEQ;   // 4096

    hipLaunchKernelGGL(lstm_mfma_kernel, dim3(bsz / NB), dim3(NTHREADS), 0, stream,
                       input, W_ih1, W_hh1, b_ih1, b_hh1,
                       W_ih2, W_hh2, b_ih2, b_hh2, W_lin, b_lin,
                       (float*)d_out);
}